// Round 3
// baseline (259.241 us; speedup 1.0000x reference)
//
#include <hip/hip_runtime.h>
#include <hip/hip_bf16.h>

#define N_Z 16384
#define M_E 4096
#define DIM 256
#define NB 2048                      // value buckets for wise kernel
#define BMIN (-6.0f)
#define BSCALE ((float)NB / 12.0f)   // buckets per unit
#define BW (12.0f / (float)NB)       // bucket width (exact: 3*2^-9)

typedef __bf16 bf16x8 __attribute__((ext_vector_type(8)));
typedef float f32x4 __attribute__((ext_vector_type(4)));

__device__ __forceinline__ unsigned short f2bf(float f) {
  unsigned u = __float_as_uint(f);
  u = (u + 0x7FFFu + ((u >> 16) & 1u)) >> 16;
  return (unsigned short)u;
}

__device__ __forceinline__ void gl2lds16(const void* g, void* s) {
  __builtin_amdgcn_global_load_lds(
      (const __attribute__((address_space(1))) unsigned*)g,
      (__attribute__((address_space(3))) unsigned*)s, 16, 0, 0);
}

// order-preserving float<->uint map (works for negatives)
__device__ __forceinline__ unsigned fmap(float f) {
  unsigned u = __float_as_uint(f);
  return (u & 0x80000000u) ? ~u : (u | 0x80000000u);
}
__device__ __forceinline__ float funmap(unsigned u) {
  return __uint_as_float((u & 0x80000000u) ? (u ^ 0x80000000u) : ~u);
}
__device__ __forceinline__ int bucketOf(float v) {
  int b = (int)((v - BMIN) * BSCALE);
  return min(max(b, 0), NB - 1);
}

// ---------------- init: d2min=+inf, wise_part=0, z2=e2=0 ----------------
__global__ void init_kernel(unsigned* __restrict__ d2min, float* __restrict__ wise_part,
                            float* __restrict__ z2, float* __restrict__ e2) {
  int i = blockIdx.x * blockDim.x + threadIdx.x;
  if (i < M_E) d2min[i] = 0x7F800000u;
  if (i < 64) wise_part[i] = 0.0f;
  if (i < N_Z) z2[i] = 0.0f;
  if (i < M_E) e2[i] = 0.0f;
}

// ---------------- fused prep: read once -> bf16 copy + transpose + row sq-norm ----------------
// grid (R/32, DIM/32), block (32, 8)
__global__ void prep_kernel(const float* __restrict__ in, float* __restrict__ outT,
                            unsigned short* __restrict__ outB, float* __restrict__ rsum, int R) {
  __shared__ float tile[32][33];
  __shared__ float rp[32];
  int r0 = blockIdx.x * 32, c0 = blockIdx.y * 32;
  int tx = threadIdx.x, ty = threadIdx.y;
  int lt = ty * 32 + tx;
  if (lt < 32) rp[lt] = 0.0f;
  __syncthreads();
#pragma unroll
  for (int i = 0; i < 4; ++i) {
    int rr = ty + 8 * i;
    float v = in[(size_t)(r0 + rr) * DIM + c0 + tx];
    tile[rr][tx] = v;
    outB[(size_t)(r0 + rr) * DIM + c0 + tx] = f2bf(v);
    atomicAdd(&rp[rr], v * v);
  }
  __syncthreads();
#pragma unroll
  for (int i = 0; i < 4; ++i)
    outT[(size_t)(c0 + ty + 8 * i) * R + r0 + tx] = tile[tx][ty + 8 * i];
  if (lt < 32) atomicAdd(&rsum[r0 + lt], rp[lt]);
}

// ---------------- fallback: f32 -> bf16 convert ----------------
__global__ void convert_kernel(const float* __restrict__ z, const float* __restrict__ e,
                               unsigned short* __restrict__ zb, unsigned short* __restrict__ eb) {
  const int NZ4 = N_Z * DIM / 4;
  const int NE4 = M_E * DIM / 4;
  int stride = gridDim.x * blockDim.x;
  for (int i = blockIdx.x * blockDim.x + threadIdx.x; i < NZ4 + NE4; i += stride) {
    const float4* src;
    unsigned short* dst;
    if (i < NZ4) {
      src = (const float4*)z + i;
      dst = zb + (size_t)i * 4;
    } else {
      int j = i - NZ4;
      src = (const float4*)e + j;
      dst = eb + (size_t)j * 4;
    }
    float4 v = *src;
    ushort4 o;
    o.x = f2bf(v.x); o.y = f2bf(v.y); o.z = f2bf(v.z); o.w = f2bf(v.w);
    *(ushort4*)dst = o;
  }
}

// ---------------- fallback: row squared-norms ----------------
__global__ void rowsum_kernel(const float* __restrict__ z, const float* __restrict__ e,
                              float* __restrict__ z2, float* __restrict__ e2) {
  int r = blockIdx.x;
  int l = threadIdx.x;
  const float* src = (r < N_Z) ? (z + (size_t)r * DIM) : (e + (size_t)(r - N_Z) * DIM);
  float4 v = ((const float4*)src)[l];
  float s = v.x * v.x + v.y * v.y + v.z * v.z + v.w * v.w;
#pragma unroll
  for (int off = 32; off; off >>= 1) s += __shfl_down(s, off);
  if (l == 0) {
    if (r < N_Z) z2[r] = s;
    else e2[r - N_Z] = s;
  }
}

// ---------------- fused bf16 GEMM (z . e^T) + min over n, per m ----------------
__global__ __launch_bounds__(256, 2) void gemm_min_kernel(
    const unsigned short* __restrict__ zb, const unsigned short* __restrict__ eb,
    const float* __restrict__ z2, const float* __restrict__ e2,
    unsigned* __restrict__ d2min) {
  __shared__ __align__(16) unsigned short lA[128 * 32];
  __shared__ __align__(16) unsigned short lB[128 * 32];

  const int t = threadIdx.x;
  const int w = t >> 6;
  const int l = t & 63;
  const int wr = w >> 1, wc = w & 1;
  // bijective XCD-aware swizzle: grid 32x128 = 4096 blocks, 4096 % 8 == 0
  int flat = blockIdx.y * 32 + blockIdx.x;
  int nf = (flat >> 3) + (flat & 7) * 512;
  const int tileM = (nf & 31) * 128;
  const int tileN = (nf >> 5) * 128;
  const int l15 = l & 15;
  const int kgr = l >> 4;

  f32x4 acc[4][4];
#pragma unroll
  for (int i = 0; i < 4; ++i)
#pragma unroll
    for (int j = 0; j < 4; ++j) acc[i][j] = (f32x4){0.f, 0.f, 0.f, 0.f};

#pragma unroll 1
  for (int k0 = 0; k0 < DIM; k0 += 32) {
#pragma unroll
    for (int i = 0; i < 2; ++i) {
      int c = i * 256 + t;
      int row = c >> 2;
      int kc = c & 3;
      int ldsbase = (i * 256 + (t & ~63)) * 8;
      gl2lds16(zb + (size_t)(tileN + row) * DIM + (k0 + kc * 8), &lA[ldsbase]);
      gl2lds16(eb + (size_t)(tileM + row) * DIM + (k0 + kc * 8), &lB[ldsbase]);
    }
    __syncthreads();

    bf16x8 a[4], b[4];
#pragma unroll
    for (int mi = 0; mi < 4; ++mi)
      a[mi] = *(const bf16x8*)&lA[(wr * 64 + mi * 16 + l15) * 32 + kgr * 8];
#pragma unroll
    for (int ni = 0; ni < 4; ++ni)
      b[ni] = *(const bf16x8*)&lB[(wc * 64 + ni * 16 + l15) * 32 + kgr * 8];
#pragma unroll
    for (int mi = 0; mi < 4; ++mi)
#pragma unroll
      for (int ni = 0; ni < 4; ++ni)
        acc[mi][ni] = __builtin_amdgcn_mfma_f32_16x16x32_bf16(a[mi], b[ni], acc[mi][ni], 0, 0, 0);
    __syncthreads();
  }

  float* z2s = (float*)lA;
  if (t < 128) z2s[t] = z2[tileN + t];
  __syncthreads();

#pragma unroll
  for (int ni = 0; ni < 4; ++ni) {
    float v = 3.4e38f;
#pragma unroll
    for (int mi = 0; mi < 4; ++mi)
#pragma unroll
      for (int r = 0; r < 4; ++r) {
        int rloc = wr * 64 + mi * 16 + kgr * 4 + r;
        v = fminf(v, z2s[rloc] - 2.0f * acc[mi][ni][r]);
      }
    v = fminf(v, __shfl_xor(v, 16));
    v = fminf(v, __shfl_xor(v, 32));
    if (l < 16) {
      int m = tileM + wc * 64 + ni * 16 + l;
      float d2 = v + e2[m];
      atomicMin(&d2min[m], __float_as_uint(d2));
    }
  }
}

// ---------------- wise build: per-dim bucket min/max + counting-sorted z column ----------------
__global__ __launch_bounds__(1024) void wbuild_kernel(
    const float* __restrict__ zT, float* __restrict__ zsorted,
    uint2* __restrict__ tminmax, unsigned* __restrict__ toff) {
  __shared__ unsigned zminU[NB];
  __shared__ unsigned zmaxU[NB];
  __shared__ unsigned zcnt[NB];
  __shared__ float stage[9216];  // half-column staging (8192 + 16 sigma slack)
  __shared__ unsigned wsum[16];

  const int d = blockIdx.x, t = threadIdx.x;
  for (int i = t; i < NB; i += 1024) {
    zminU[i] = 0xFFFFFFFFu;
    zmaxU[i] = 0u;
    zcnt[i] = 0u;
  }
  __syncthreads();

  float zv[16];
  int zbk[16];
  const float4* p = (const float4*)(zT + (size_t)d * N_Z);
#pragma unroll
  for (int i = 0; i < 4; ++i) {
    float4 v = p[i * 1024 + t];
    zv[4 * i + 0] = v.x; zv[4 * i + 1] = v.y; zv[4 * i + 2] = v.z; zv[4 * i + 3] = v.w;
  }
#pragma unroll
  for (int i = 0; i < 16; ++i) {
    zbk[i] = bucketOf(zv[i]);
    unsigned u = fmap(zv[i]);
    atomicMin(&zminU[zbk[i]], u);
    atomicMax(&zmaxU[zbk[i]], u);
    atomicAdd(&zcnt[zbk[i]], 1u);
  }
  __syncthreads();

  // exclusive prefix sum over zcnt (2 buckets/thread), write starts + tables
  unsigned c0 = zcnt[2 * t], c1 = zcnt[2 * t + 1];
  unsigned ts2 = c0 + c1, s = ts2;
#pragma unroll
  for (int o = 1; o < 64; o <<= 1) {
    unsigned vv = __shfl_up(s, o);
    if ((t & 63) >= o) s += vv;
  }
  if ((t & 63) == 63) wsum[t >> 6] = s;
  __syncthreads();
  if (t == 0) {
    unsigned a = 0;
#pragma unroll
    for (int i = 0; i < 16; ++i) { unsigned vv = wsum[i]; wsum[i] = a; a += vv; }
  }
  __syncthreads();
  unsigned texcl = wsum[t >> 6] + (s - ts2);
  zcnt[2 * t] = texcl;
  zcnt[2 * t + 1] = texcl + c0;
  toff[(size_t)d * NB + 2 * t] = texcl;
  toff[(size_t)d * NB + 2 * t + 1] = texcl + c0;
  uint2 m0; m0.x = zminU[2 * t];     m0.y = zmaxU[2 * t];
  uint2 m1; m1.x = zminU[2 * t + 1]; m1.y = zmaxU[2 * t + 1];
  tminmax[(size_t)d * NB + 2 * t] = m0;
  tminmax[(size_t)d * NB + 2 * t + 1] = m1;
  __syncthreads();

  // scatter into LDS stage in two halves (coalesced global write-out)
  float* zsd = zsorted + (size_t)d * N_Z;
#pragma unroll 1
  for (int h = 0; h < 2; ++h) {
    unsigned base = zcnt[h * 1024];
    unsigned endv = (h == 0) ? zcnt[1024] : (unsigned)N_Z;
    zmaxU[h * 1024 + t] = zcnt[h * 1024 + t] - base;  // reuse zmaxU as cursor
    __syncthreads();
#pragma unroll
    for (int i = 0; i < 16; ++i) {
      int b = zbk[i];
      if ((b >> 10) == h) {
        unsigned pos = atomicAdd(&zmaxU[b], 1u);
        stage[pos] = zv[i];
      }
    }
    __syncthreads();
    unsigned cnt = endv - base;
    for (unsigned i = t; i < cnt; i += 1024) zsd[base + i] = stage[i];
    __syncthreads();
  }
}

// ---------------- wise query: 4 blocks/dim, 1 atomic/block ----------------
__global__ __launch_bounds__(256) void wquery_kernel(
    const float* __restrict__ eT, const float* __restrict__ zsorted,
    const uint2* __restrict__ tminmax, const unsigned* __restrict__ toff,
    float* __restrict__ wise_part) {
  __shared__ uint2 mm[NB];
  __shared__ unsigned off[NB + 1];
  __shared__ float bsum[4];
  const int d = blockIdx.y, sl = blockIdx.x, t = threadIdx.x;

  for (int i = t; i < NB; i += 256) {
    mm[i] = tminmax[(size_t)d * NB + i];
    off[i] = toff[(size_t)d * NB + i];
  }
  if (t == 0) off[NB] = N_Z;
  __syncthreads();

  const float* zs = zsorted + (size_t)d * N_Z;
  const float* ec = eT + (size_t)d * M_E;
  float acc = 0.0f;
#pragma unroll
  for (int q = 0; q < 4; ++q) {
    float ev = ec[sl * 1024 + q * 256 + t];
    int b0 = bucketOf(ev);
    float best2 = 3.4e38f;
    unsigned j0 = off[b0], j1 = off[b0 + 1];
    for (unsigned j = j0; j < j1; ++j) {
      float dd = zs[j] - ev;
      best2 = fminf(best2, dd * dd);
    }
    for (int r = 1; r < NB; ++r) {
      int bl = b0 - r, br = b0 + r;
      float edgeL = BMIN + (float)(bl + 1) * BW;
      float edgeR = BMIN + (float)br * BW;
      float dL = ev - edgeL, dR = edgeR - ev;
      bool doL = (bl >= 0) && (dL * dL < best2);
      bool doR = (br < NB) && (dR * dR < best2);
      if (!doL && !doR) break;
      if (doL) {
        unsigned u = mm[bl].y;
        if (u != 0u) { float dd = funmap(u) - ev; best2 = fminf(best2, dd * dd); }
      }
      if (doR) {
        unsigned u = mm[br].x;
        if (u != 0xFFFFFFFFu) { float dd = funmap(u) - ev; best2 = fminf(best2, dd * dd); }
      }
    }
    acc += best2;
  }
#pragma unroll
  for (int o = 32; o; o >>= 1) acc += __shfl_down(acc, o);
  if ((t & 63) == 0) bsum[t >> 6] = acc;
  __syncthreads();
  if (t == 0) {
    float ssum = bsum[0] + bsum[1] + bsum[2] + bsum[3];
    atomicAdd(&wise_part[(d * 4 + sl) & 63], ssum);
  }
}

// ---------------- fallback wise (single-kernel, R2 version) ----------------
__global__ __launch_bounds__(1024) void wise_kernel(
    const float* __restrict__ z, const float* __restrict__ e,
    const float* __restrict__ zT, const float* __restrict__ eT,
    int transposed, float* __restrict__ wise_sum) {
  __shared__ unsigned zminU[NB];
  __shared__ unsigned zmaxU[NB];
  __shared__ unsigned eoff[NB];
  __shared__ float esorted[M_E];
  __shared__ unsigned eres[M_E];
  __shared__ unsigned wsum[16];

  const int d = blockIdx.x;
  const int t = threadIdx.x;

  for (int i = t; i < NB; i += 1024) {
    zminU[i] = 0xFFFFFFFFu;
    zmaxU[i] = 0u;
    eoff[i] = 0u;
  }
  __syncthreads();

  float zv[16];
  if (transposed) {
    const float4* p = (const float4*)(zT + (size_t)d * N_Z);
#pragma unroll
    for (int i = 0; i < 4; ++i) {
      float4 v = p[i * 1024 + t];
      zv[i * 4 + 0] = v.x; zv[i * 4 + 1] = v.y; zv[i * 4 + 2] = v.z; zv[i * 4 + 3] = v.w;
    }
  } else {
#pragma unroll
    for (int i = 0; i < 16; ++i) zv[i] = z[(size_t)(i * 1024 + t) * DIM + d];
  }
#pragma unroll
  for (int i = 0; i < 16; ++i) {
    int b = bucketOf(zv[i]);
    unsigned u = fmap(zv[i]);
    atomicMin(&zminU[b], u);
    atomicMax(&zmaxU[b], u);
  }

  float ev4[4];
  int ebk[4];
  if (transposed) {
    float4 v = ((const float4*)(eT + (size_t)d * M_E))[t];
    ev4[0] = v.x; ev4[1] = v.y; ev4[2] = v.z; ev4[3] = v.w;
  } else {
#pragma unroll
    for (int i = 0; i < 4; ++i) ev4[i] = e[(size_t)(t * 4 + i) * DIM + d];
  }
#pragma unroll
  for (int i = 0; i < 4; ++i) {
    ebk[i] = bucketOf(ev4[i]);
    atomicAdd(&eoff[ebk[i]], 1u);
  }
  __syncthreads();

  unsigned c0 = eoff[2 * t], c1 = eoff[2 * t + 1];
  unsigned ts = c0 + c1;
  unsigned s = ts;
#pragma unroll
  for (int o = 1; o < 64; o <<= 1) {
    unsigned v = __shfl_up(s, o);
    if ((t & 63) >= o) s += v;
  }
  if ((t & 63) == 63) wsum[t >> 6] = s;
  __syncthreads();
  if (t == 0) {
    unsigned acc = 0;
#pragma unroll
    for (int i = 0; i < 16; ++i) { unsigned v = wsum[i]; wsum[i] = acc; acc += v; }
  }
  __syncthreads();
  unsigned texcl = wsum[t >> 6] + (s - ts);
  eoff[2 * t] = texcl;
  eoff[2 * t + 1] = texcl + c0;
  __syncthreads();

#pragma unroll
  for (int i = 0; i < 4; ++i) {
    unsigned pos = atomicAdd(&eoff[ebk[i]], 1u);
    esorted[pos] = ev4[i];
  }
  __syncthreads();

#pragma unroll
  for (int q = 0; q < 4; ++q) {
    int idx = q * 1024 + t;
    float ev = esorted[idx];
    int b0 = bucketOf(ev);
    float best2 = 3.4e38f;
    unsigned mn = zminU[b0], mx = zmaxU[b0];
    if (mn != 0xFFFFFFFFu) {
      float dd = funmap(mn) - ev;
      best2 = dd * dd;
      dd = funmap(mx) - ev;
      best2 = fminf(best2, dd * dd);
    }
    for (int r = 1; r < NB; ++r) {
      int bl = b0 - r, br = b0 + r;
      float edgeL = BMIN + (float)(b0 - r + 1) * BW;
      float edgeR = BMIN + (float)(b0 + r) * BW;
      float dL = ev - edgeL;
      float dR = edgeR - ev;
      bool doL = (bl >= 0) && (dL * dL < best2);
      bool doR = (br < NB) && (dR * dR < best2);
      if (!doL && !doR) break;
      if (doL) {
        unsigned u = zmaxU[bl];
        if (u != 0u) { float dd = funmap(u) - ev; best2 = fminf(best2, dd * dd); }
      }
      if (doR) {
        unsigned u = zminU[br];
        if (u != 0xFFFFFFFFu) { float dd = funmap(u) - ev; best2 = fminf(best2, dd * dd); }
      }
    }
    eres[idx] = __float_as_uint(best2);
  }
  __syncthreads();

#pragma unroll
  for (int i = 0; i < 16; ++i) {
    int b = bucketOf(zv[i]);
    unsigned s0 = (b == 0) ? 0u : eoff[b - 1];
    unsigned s1 = eoff[b];
    for (unsigned j = s0; j < s1; ++j) {
      float dd = zv[i] - esorted[j];
      atomicMin(&eres[j], __float_as_uint(dd * dd));
    }
  }
  __syncthreads();

  float loc = 0.0f;
  for (int i = t; i < M_E; i += 1024) loc += __uint_as_float(eres[i]);
#pragma unroll
  for (int off = 32; off; off >>= 1) loc += __shfl_down(loc, off);
  if ((t & 63) == 0) atomicAdd(wise_sum, loc);
}

// ---------------- final reduce ----------------
__global__ void final_kernel(const unsigned* __restrict__ d2min,
                             const float* __restrict__ wise_part, float* __restrict__ out) {
  __shared__ float red[4];
  int t = threadIdx.x;
  float s = 0.0f;
  for (int m = t; m < M_E; m += 256) s += __uint_as_float(d2min[m]);
#pragma unroll
  for (int off = 32; off; off >>= 1) s += __shfl_down(s, off);
  if ((t & 63) == 0) red[t >> 6] = s;
  __syncthreads();
  if (t == 0) {
    float tot = red[0] + red[1] + red[2] + red[3];
    out[0] = tot / (float)M_E;
    float w = 0.0f;
    for (int i = 0; i < 64; ++i) w += wise_part[i];
    out[1] = w / ((float)M_E * (float)DIM);
  }
}

extern "C" void kernel_launch(void* const* d_in, const int* in_sizes, int n_in,
                              void* d_out, int out_size, void* d_ws, size_t ws_size,
                              hipStream_t stream) {
  const float* z = (const float*)d_in[0];
  const float* e = (const float*)d_in[1];
  float* out = (float*)d_out;

  char* ws = (char*)d_ws;
  unsigned short* zb = (unsigned short*)ws;                 // 8 MiB
  unsigned short* eb = (unsigned short*)(ws + 8388608);     // 2 MiB
  float* z2 = (float*)(ws + 10485760);                      // 64 KiB
  float* e2 = (float*)(ws + 10551296);                      // 16 KiB
  unsigned* d2min = (unsigned*)(ws + 10567680);             // 16 KiB
  float* wise_part = (float*)(ws + 10584064);               // 256 B
  float* zT = (float*)(ws + 11534336);                      // 16 MiB
  float* eT = (float*)(ws + 28311552);                      // 4 MiB
  float* zsorted = (float*)(ws + 32505856);                 // 16 MiB
  uint2* tminmax = (uint2*)(ws + 49283072);                 // 4 MiB
  unsigned* toff = (unsigned*)(ws + 53477376);              // 2 MiB -> 55574528

  const size_t WS_T = 32505856;
  const size_t WS_NEW = 55574528;
  int transposed = (ws_size >= WS_T) ? 1 : 0;
  int newpath = (ws_size >= WS_NEW) ? 1 : 0;

  init_kernel<<<64, 256, 0, stream>>>(d2min, wise_part, z2, e2);
  if (transposed) {
    prep_kernel<<<dim3(N_Z / 32, DIM / 32), dim3(32, 8), 0, stream>>>(z, zT, zb, z2, N_Z);
    prep_kernel<<<dim3(M_E / 32, DIM / 32), dim3(32, 8), 0, stream>>>(e, eT, eb, e2, M_E);
  } else {
    convert_kernel<<<2048, 256, 0, stream>>>(z, e, zb, eb);
    rowsum_kernel<<<N_Z + M_E, 64, 0, stream>>>(z, e, z2, e2);
  }
  gemm_min_kernel<<<dim3(32, 128), 256, 0, stream>>>(zb, eb, z2, e2, d2min);
  if (newpath) {
    wbuild_kernel<<<DIM, 1024, 0, stream>>>(zT, zsorted, tminmax, toff);
    wquery_kernel<<<dim3(4, DIM), 256, 0, stream>>>(eT, zsorted, tminmax, toff, wise_part);
  } else {
    wise_kernel<<<DIM, 1024, 0, stream>>>(z, e, zT, eT, transposed, wise_part);
  }
  final_kernel<<<1, 256, 0, stream>>>(d2min, wise_part, out);
}

// Round 4
// 241.856 us; speedup vs baseline: 1.0719x; 1.0719x over previous
//
#include <hip/hip_runtime.h>
#include <hip/hip_bf16.h>

#define N_Z 16384
#define M_E 4096
#define DIM 256
#define NB 2048                      // value buckets for wise kernel
#define BMIN (-6.0f)
#define BSCALE ((float)NB / 12.0f)   // buckets per unit (inexact; fixed up)
#define BW (12.0f / (float)NB)       // bucket width (exact: 3*2^-9)

typedef __bf16 bf16x8 __attribute__((ext_vector_type(8)));
typedef float f32x4 __attribute__((ext_vector_type(4)));

__device__ __forceinline__ unsigned short f2bf(float f) {
  unsigned u = __float_as_uint(f);
  u = (u + 0x7FFFu + ((u >> 16) & 1u)) >> 16;
  return (unsigned short)u;
}

__device__ __forceinline__ void gl2lds16(const void* g, void* s) {
  __builtin_amdgcn_global_load_lds(
      (const __attribute__((address_space(1))) unsigned*)g,
      (__attribute__((address_space(3))) unsigned*)s, 16, 0, 0);
}

// bucket edges edge(k) = BMIN + k*BW are EXACT in f32 ((3k-3072)*2^-9),
// so fix up the inexact *BSCALE rounding to make slice bounds sound.
__device__ __forceinline__ int bucketFix(float v) {
  int b = (int)((v - BMIN) * BSCALE);
  b = min(max(b, 0), NB - 1);
  while (b > 0 && v < BMIN + (float)b * BW) --b;
  while (b < NB - 1 && v >= BMIN + (float)(b + 1) * BW) ++b;
  return b;
}

// ---------------- init: d2min=+inf, wise_part=0, z2=e2=0 ----------------
__global__ void init_kernel(unsigned* __restrict__ d2min, float* __restrict__ wise_part,
                            float* __restrict__ z2, float* __restrict__ e2) {
  int i = blockIdx.x * blockDim.x + threadIdx.x;
  if (i < M_E) d2min[i] = 0x7F800000u;
  if (i < 64) wise_part[i] = 0.0f;
  if (i < N_Z) z2[i] = 0.0f;
  if (i < M_E) e2[i] = 0.0f;
}

// ---------------- fused prep: read once -> bf16 copy + transpose + row sq-norm ----------------
__global__ void prep_kernel(const float* __restrict__ in, float* __restrict__ outT,
                            unsigned short* __restrict__ outB, float* __restrict__ rsum, int R) {
  __shared__ float tile[32][33];
  __shared__ float rp[32];
  int r0 = blockIdx.x * 32, c0 = blockIdx.y * 32;
  int tx = threadIdx.x, ty = threadIdx.y;
  int lt = ty * 32 + tx;
  if (lt < 32) rp[lt] = 0.0f;
  __syncthreads();
#pragma unroll
  for (int i = 0; i < 4; ++i) {
    int rr = ty + 8 * i;
    float v = in[(size_t)(r0 + rr) * DIM + c0 + tx];
    tile[rr][tx] = v;
    outB[(size_t)(r0 + rr) * DIM + c0 + tx] = f2bf(v);
    atomicAdd(&rp[rr], v * v);
  }
  __syncthreads();
#pragma unroll
  for (int i = 0; i < 4; ++i)
    outT[(size_t)(c0 + ty + 8 * i) * R + r0 + tx] = tile[tx][ty + 8 * i];
  if (lt < 32) atomicAdd(&rsum[r0 + lt], rp[lt]);
}

// ---------------- fused bf16 GEMM (z . e^T) + min over n, per m ----------------
__global__ __launch_bounds__(256, 2) void gemm_min_kernel(
    const unsigned short* __restrict__ zb, const unsigned short* __restrict__ eb,
    const float* __restrict__ z2, const float* __restrict__ e2,
    unsigned* __restrict__ d2min) {
  __shared__ __align__(16) unsigned short lA[128 * 32];
  __shared__ __align__(16) unsigned short lB[128 * 32];

  const int t = threadIdx.x;
  const int w = t >> 6;
  const int l = t & 63;
  const int wr = w >> 1, wc = w & 1;
  int flat = blockIdx.y * 32 + blockIdx.x;
  int nf = (flat >> 3) + (flat & 7) * 512;
  const int tileM = (nf & 31) * 128;
  const int tileN = (nf >> 5) * 128;
  const int l15 = l & 15;
  const int kgr = l >> 4;

  f32x4 acc[4][4];
#pragma unroll
  for (int i = 0; i < 4; ++i)
#pragma unroll
    for (int j = 0; j < 4; ++j) acc[i][j] = (f32x4){0.f, 0.f, 0.f, 0.f};

#pragma unroll 1
  for (int k0 = 0; k0 < DIM; k0 += 32) {
#pragma unroll
    for (int i = 0; i < 2; ++i) {
      int c = i * 256 + t;
      int row = c >> 2;
      int kc = c & 3;
      int ldsbase = (i * 256 + (t & ~63)) * 8;
      gl2lds16(zb + (size_t)(tileN + row) * DIM + (k0 + kc * 8), &lA[ldsbase]);
      gl2lds16(eb + (size_t)(tileM + row) * DIM + (k0 + kc * 8), &lB[ldsbase]);
    }
    __syncthreads();

    bf16x8 a[4], b[4];
#pragma unroll
    for (int mi = 0; mi < 4; ++mi)
      a[mi] = *(const bf16x8*)&lA[(wr * 64 + mi * 16 + l15) * 32 + kgr * 8];
#pragma unroll
    for (int ni = 0; ni < 4; ++ni)
      b[ni] = *(const bf16x8*)&lB[(wc * 64 + ni * 16 + l15) * 32 + kgr * 8];
#pragma unroll
    for (int mi = 0; mi < 4; ++mi)
#pragma unroll
      for (int ni = 0; ni < 4; ++ni)
        acc[mi][ni] = __builtin_amdgcn_mfma_f32_16x16x32_bf16(a[mi], b[ni], acc[mi][ni], 0, 0, 0);
    __syncthreads();
  }

  float* z2s = (float*)lA;
  if (t < 128) z2s[t] = z2[tileN + t];
  __syncthreads();

#pragma unroll
  for (int ni = 0; ni < 4; ++ni) {
    float v = 3.4e38f;
#pragma unroll
    for (int mi = 0; mi < 4; ++mi)
#pragma unroll
      for (int r = 0; r < 4; ++r) {
        int rloc = wr * 64 + mi * 16 + kgr * 4 + r;
        v = fminf(v, z2s[rloc] - 2.0f * acc[mi][ni][r]);
      }
    v = fminf(v, __shfl_xor(v, 16));
    v = fminf(v, __shfl_xor(v, 32));
    if (l < 16) {
      int m = tileM + wc * 64 + ni * 16 + l;
      float d2 = v + e2[m];
      atomicMin(&d2min[m], __float_as_uint(d2));
    }
  }
}

// ---------------- wise: one block per dim; counting-sorted z column kept in LDS ----------------
// Dynamic LDS: float zs[N_Z] (64KB) + unsigned off[NB] (8KB) + unsigned wsum[16].
// Query-driven: each e scans its own bucket slice + neighbor slices during
// expansion; termination via exact bucket-edge bound. No e-scatter, no eres,
// no min/max tables.
__global__ __launch_bounds__(1024) void wise2_kernel(
    const float* __restrict__ zT, const float* __restrict__ eT,
    float* __restrict__ wise_part) {
  extern __shared__ __align__(16) char smem[];
  float* zs = (float*)smem;                       // N_Z floats
  unsigned* off = (unsigned*)(smem + N_Z * 4);    // NB
  unsigned* wsum = off + NB;                      // 16

  const int d = blockIdx.x, t = threadIdx.x;

  for (int i = t; i < NB; i += 1024) off[i] = 0u;
  __syncthreads();

  // load z column (16/thread, coalesced), histogram
  float zv[16];
  int zbk[16];
  const float4* p = (const float4*)(zT + (size_t)d * N_Z);
#pragma unroll
  for (int i = 0; i < 4; ++i) {
    float4 v = p[i * 1024 + t];
    zv[4 * i + 0] = v.x; zv[4 * i + 1] = v.y; zv[4 * i + 2] = v.z; zv[4 * i + 3] = v.w;
  }
#pragma unroll
  for (int i = 0; i < 16; ++i) {
    zbk[i] = bucketFix(zv[i]);
    atomicAdd(&off[zbk[i]], 1u);
  }
  __syncthreads();

  // exclusive prefix sum (2 buckets/thread); off[b] becomes start cursor
  unsigned c0 = off[2 * t], c1 = off[2 * t + 1];
  unsigned ts2 = c0 + c1, s = ts2;
#pragma unroll
  for (int o = 1; o < 64; o <<= 1) {
    unsigned vv = __shfl_up(s, o);
    if ((t & 63) >= o) s += vv;
  }
  if ((t & 63) == 63) wsum[t >> 6] = s;
  __syncthreads();
  if (t == 0) {
    unsigned a = 0;
#pragma unroll
    for (int i = 0; i < 16; ++i) { unsigned vv = wsum[i]; wsum[i] = a; a += vv; }
  }
  __syncthreads();
  unsigned texcl = wsum[t >> 6] + (s - ts2);
  __syncthreads();  // all reads of off done before overwrite
  off[2 * t] = texcl;
  off[2 * t + 1] = texcl + c0;
  __syncthreads();

  // scatter z into LDS bucket-ordered array; off[b] -> end(b)
#pragma unroll
  for (int i = 0; i < 16; ++i) {
    unsigned pos = atomicAdd(&off[zbk[i]], 1u);
    zs[pos] = zv[i];
  }
  __syncthreads();

  // queries: 4/thread, coalesced e loads
  const float* ec = eT + (size_t)d * M_E;
  float accq = 0.0f;
#pragma unroll
  for (int q = 0; q < 4; ++q) {
    float ev = ec[q * 1024 + t];
    int b0 = bucketFix(ev);
    unsigned s0 = b0 ? off[b0 - 1] : 0u;
    unsigned s1 = off[b0];
    float best2 = 3.4e38f;
    // seeds: members of nearest non-empty buckets in bucket order
    {
      unsigned js = min(s0, (unsigned)(N_Z - 1));
      float dd = zs[js] - ev;
      best2 = dd * dd;
      if (s0 > 0) { dd = zs[s0 - 1] - ev; best2 = fminf(best2, dd * dd); }
    }
    for (unsigned j = s0; j < s1; ++j) {
      float dd = zs[j] - ev;
      best2 = fminf(best2, dd * dd);
    }
    for (int r = 1; r < NB; ++r) {
      int bl = b0 - r, br = b0 + r;
      float edgeL = BMIN + (float)(bl + 1) * BW;  // all z in bl <= edgeL
      float edgeR = BMIN + (float)br * BW;        // all z in br >= edgeR
      float dL = ev - edgeL, dR = edgeR - ev;
      bool doL = (bl >= 0) && (dL * dL < best2);
      bool doR = (br < NB) && (dR * dR < best2);
      if (!doL && !doR) break;
      if (doL) {
        unsigned a0 = bl ? off[bl - 1] : 0u, a1 = off[bl];
        for (unsigned j = a0; j < a1; ++j) {
          float dd = zs[j] - ev;
          best2 = fminf(best2, dd * dd);
        }
      }
      if (doR) {
        unsigned a0 = off[br - 1], a1 = off[br];
        for (unsigned j = a0; j < a1; ++j) {
          float dd = zs[j] - ev;
          best2 = fminf(best2, dd * dd);
        }
      }
    }
    accq += best2;
  }

  // reduce block sum -> one atomic
#pragma unroll
  for (int o = 32; o; o >>= 1) accq += __shfl_down(accq, o);
  __syncthreads();  // wsum reuse safe
  if ((t & 63) == 0) wsum[t >> 6] = __float_as_uint(accq);
  __syncthreads();
  if (t == 0) {
    float ssum = 0.0f;
#pragma unroll
    for (int i = 0; i < 16; ++i) ssum += __uint_as_float(wsum[i]);
    atomicAdd(&wise_part[d & 63], ssum);
  }
}

// ---------------- final reduce ----------------
__global__ void final_kernel(const unsigned* __restrict__ d2min,
                             const float* __restrict__ wise_part, float* __restrict__ out) {
  __shared__ float red[4];
  int t = threadIdx.x;
  float s = 0.0f;
  for (int m = t; m < M_E; m += 256) s += __uint_as_float(d2min[m]);
#pragma unroll
  for (int off = 32; off; off >>= 1) s += __shfl_down(s, off);
  if ((t & 63) == 0) red[t >> 6] = s;
  __syncthreads();
  if (t == 0) {
    float tot = red[0] + red[1] + red[2] + red[3];
    out[0] = tot / (float)M_E;
    float w = 0.0f;
    for (int i = 0; i < 64; ++i) w += wise_part[i];
    out[1] = w / ((float)M_E * (float)DIM);
  }
}

extern "C" void kernel_launch(void* const* d_in, const int* in_sizes, int n_in,
                              void* d_out, int out_size, void* d_ws, size_t ws_size,
                              hipStream_t stream) {
  const float* z = (const float*)d_in[0];
  const float* e = (const float*)d_in[1];
  float* out = (float*)d_out;

  char* ws = (char*)d_ws;
  unsigned short* zb = (unsigned short*)ws;                 // 8 MiB
  unsigned short* eb = (unsigned short*)(ws + 8388608);     // 2 MiB
  float* z2 = (float*)(ws + 10485760);                      // 64 KiB
  float* e2 = (float*)(ws + 10551296);                      // 16 KiB
  unsigned* d2min = (unsigned*)(ws + 10567680);             // 16 KiB
  float* wise_part = (float*)(ws + 10584064);               // 256 B
  float* zT = (float*)(ws + 11534336);                      // 16 MiB
  float* eT = (float*)(ws + 28311552);                      // 4 MiB -> 32505856

  const size_t LDS_WISE = (size_t)N_Z * 4 + (size_t)NB * 4 + 64;  // 73792 B
  static int attr_done = 0;
  if (!attr_done) {
    (void)hipFuncSetAttribute((const void*)wise2_kernel,
                              hipFuncAttributeMaxDynamicSharedMemorySize, (int)LDS_WISE);
    attr_done = 1;
  }

  init_kernel<<<64, 256, 0, stream>>>(d2min, wise_part, z2, e2);
  prep_kernel<<<dim3(N_Z / 32, DIM / 32), dim3(32, 8), 0, stream>>>(z, zT, zb, z2, N_Z);
  prep_kernel<<<dim3(M_E / 32, DIM / 32), dim3(32, 8), 0, stream>>>(e, eT, eb, e2, M_E);
  gemm_min_kernel<<<dim3(32, 128), 256, 0, stream>>>(zb, eb, z2, e2, d2min);
  wise2_kernel<<<DIM, 1024, LDS_WISE, stream>>>(zT, eT, wise_part);
  final_kernel<<<1, 256, 0, stream>>>(d2min, wise_part, out);
}